// Round 3
// baseline (110.588 us; speedup 1.0000x reference)
//
#include <hip/hip_runtime.h>

#define N        384
#define DIM      256
#define D4       (DIM / 4)       // 64 float4 per row
#define MARGIN_F 0.2f
#define NANCH    2               // anchors per block
#define NBLK     (N / NANCH)     // 192 blocks
#define NTHR     384
#define NWAVE    (NTHR / 64)     // 6 waves
#define MAXPOS   64              // labels ~ Binom(384,1/32): mean 12, 64 is >14 sigma

// Workspace: [0]=sum(float) [1]=cnt(uint) [2]=done(uint) — zeroed by 12B memset.

__global__ __launch_bounds__(NTHR) void fused_all(
    const float* __restrict__ emb, const int* __restrict__ labels,
    float* __restrict__ accum_sum, unsigned int* __restrict__ accum_cnt,
    unsigned int* __restrict__ done_cnt, float* __restrict__ out)
{
    const int i0   = blockIdx.x * NANCH;
    const int tid  = threadIdx.x;
    const int wave = tid >> 6, lane = tid & 63;

    __shared__ float invn[N];            // 1/max(norm,1e-12)
    __shared__ float sqn[N];             // sum(e_norm^2)  (~1.0, ref recomputes)
    __shared__ float ei[NANCH][DIM];     // normalized anchor rows
    __shared__ float Drow[NANCH][N];     // distance rows (never touch global)
    __shared__ int   lab[N];
    __shared__ int   posList[NANCH][MAXPOS];
    __shared__ int   posCnt[NANCH];
    __shared__ float        sredS[NWAVE];
    __shared__ unsigned int sredC[NWAVE];

    // ---- Phase A: every block computes all row norms itself (no global dep).
    // Wave w owns rows w, w+6, ...: one coalesced float4 row-load + shuffle reduce.
    const float4* emb4 = (const float4*)emb;
    for (int r = wave; r < N; r += NWAVE) {
        const float4 v = emb4[r * D4 + lane];     // 64 lanes x 16B = whole row
        float s = v.x*v.x + v.y*v.y + v.z*v.z + v.w*v.w;
        #pragma unroll
        for (int off = 32; off > 0; off >>= 1) s += __shfl_down(s, off, 64);
        if (lane == 0) {
            const float inv = 1.0f / fmaxf(sqrtf(s), 1e-12f);
            invn[r] = inv;
            sqn[r]  = s * inv * inv;              // matches ref's recompute on e_norm
        }
    }
    if (tid < NANCH) posCnt[tid] = 0;
    lab[tid] = labels[tid];
    __syncthreads();

    // normalized anchors into LDS
    for (int t = tid; t < NANCH * DIM; t += NTHR) {
        const int a = t >> 8, k = t & (DIM - 1);
        ei[a][k] = emb[(i0 + a) * DIM + k] * invn[i0 + a];
    }
    __syncthreads();

    // ---- Phase B: distance rows. Thread tid owns column j=tid; float4 down row j.
    // dot_norm = invj * sum(raw_j[k] * ei[a][k])   (ei already normalized)
    const float4* __restrict__ rowj = emb4 + (size_t)tid * D4;
    const float4* __restrict__ e0   = (const float4*)ei[0];
    const float4* __restrict__ e1   = (const float4*)ei[1];
    float acc0 = 0.0f, acc1 = 0.0f;
    #pragma unroll 8
    for (int k = 0; k < D4; ++k) {
        const float4 v  = rowj[k];                // global_load_dwordx4, 8 in flight
        const float4 a0 = e0[k];                  // ds_read_b128 broadcast (free)
        const float4 a1 = e1[k];
        acc0 += v.x*a0.x + v.y*a0.y + v.z*a0.z + v.w*a0.w;
        acc1 += v.x*a1.x + v.y*a1.y + v.z*a1.z + v.w*a1.w;
    }
    const float invj = invn[tid];
    const float sqj  = sqn[tid];
    {
        float d2 = fmaxf(sqn[i0]     + sqj - 2.0f * acc0 * invj, 0.0f);
        Drow[0][tid] = (d2 > 0.0f) ? sqrtf(d2) : 0.0f;   // ref: sqrt(where(pos,d2,1))*pos
        d2       = fmaxf(sqn[i0 + 1] + sqj - 2.0f * acc1 * invj, 0.0f);
        Drow[1][tid] = (d2 > 0.0f) ? sqrtf(d2) : 0.0f;
    }
    __syncthreads();

    // ---- Phase C: positive lists for both anchors
    const int lj = lab[tid];
    #pragma unroll
    for (int a = 0; a < NANCH; ++a) {
        const int ia = i0 + a;
        if (lj == lab[ia] && tid != ia)
            posList[a][atomicAdd(&posCnt[a], 1)] = tid;
    }
    __syncthreads();

    // ---- Phase D: semihard accumulation; thread tid owns negative k=tid
    float        lsum = 0.0f;
    unsigned int lcnt = 0u;
    #pragma unroll
    for (int a = 0; a < NANCH; ++a) {
        const int   li = lab[i0 + a];
        const float dk = Drow[a][tid];            // an (if tid is a negative)
        if (lj != li) {
            const int np = posCnt[a];             // ~11 positives
            for (int p = 0; p < np; ++p) {
                const float tm = dk - Drow[a][posList[a][p]];   // an - ap
                if (tm > 0.0f && tm <= MARGIN_F) {
                    const float l = MARGIN_F - tm;              // max(MARGIN-tm,0)
                    lsum += l;
                    if (l > 0.0f) lcnt++;                       // strict losses>0 count
                }
            }
        }
    }

    // ---- block reduce, device accumulate, last-block finalize
    #pragma unroll
    for (int off = 32; off > 0; off >>= 1) {
        lsum += __shfl_down(lsum, off, 64);
        lcnt += __shfl_down(lcnt, off, 64);
    }
    if (lane == 0) { sredS[wave] = lsum; sredC[wave] = lcnt; }
    __syncthreads();

    if (tid == 0) {
        float        S = 0.0f;
        unsigned int C = 0u;
        #pragma unroll
        for (int w = 0; w < NWAVE; ++w) { S += sredS[w]; C += sredC[w]; }
        if (S != 0.0f || C != 0u) {
            atomicAdd(accum_sum, S);
            atomicAdd(accum_cnt, C);
        }
        __threadfence();                           // order adds before done++
        const unsigned int prev = atomicAdd(done_cnt, 1);
        if (prev == NBLK - 1) {                    // last block computes the mean
            const float        Sall = atomicAdd(accum_sum, 0.0f);
            const unsigned int Call = atomicAdd(accum_cnt, 0u);
            out[0] = (Call > 0u) ? (Sall / (float)Call) : 0.0f;
        }
    }
}

extern "C" void kernel_launch(void* const* d_in, const int* in_sizes, int n_in,
                              void* d_out, int out_size, void* d_ws, size_t ws_size,
                              hipStream_t stream) {
    const float* emb    = (const float*)d_in[0];   // (384, 256) fp32
    const int*   labels = (const int*)d_in[1];     // (384,) int32
    float*       out    = (float*)d_out;           // scalar fp32

    float*        accum_sum = (float*)d_ws;
    unsigned int* accum_cnt = (unsigned int*)accum_sum + 1;
    unsigned int* done_cnt  = (unsigned int*)accum_sum + 2;

    hipMemsetAsync(d_ws, 0, 12, stream);           // zero sum/cnt/done (graph-legal)
    fused_all<<<NBLK, NTHR, 0, stream>>>(emb, labels,
                                         accum_sum, accum_cnt, done_cnt, out);
}

// Round 4
// 77.289 us; speedup vs baseline: 1.4308x; 1.4308x over previous
//
#include <hip/hip_runtime.h>

#define N        384
#define DIM      256
#define D4       (DIM / 4)       // 64 float4 per row
#define MARGIN_F 0.2f
#define NANCH    2               // anchors per fused block
#define NBLK     (N / NANCH)     // 192 blocks
#define NTHR     384
#define NWAVE    (NTHR / 64)     // 6 waves
#define MAXPOS   64              // labels ~ Binom(384,1/32): mean 12; 64 is >14 sigma

// ---------------------------------------------------------------------------
// Workspace layout:
//   [0..15]   accum: sum(float), cnt(uint), done(uint)  — zeroed by 16B memset
//   [16..]    eTv : N*DIM floats as float4[k4][j]  (k4-major, j fastest)
//             -> K2's k-loop load eTv[k4*N + tid] is lane-consecutive 16B
//   then      sqn : N floats, sum(e_norm^2) per row (~1.0; ref recomputes it)
// ---------------------------------------------------------------------------

__global__ __launch_bounds__(64) void norm_kernel(
    const float* __restrict__ emb, float4* __restrict__ eTv,
    float* __restrict__ sqn)
{
    const int row  = blockIdx.x;       // 0..N-1
    const int lane = threadIdx.x;      // 0..63, one float4 each = whole row

    const float4 v = ((const float4*)emb)[row * D4 + lane];   // coalesced 1KB/wave
    float s = v.x*v.x + v.y*v.y + v.z*v.z + v.w*v.w;
    #pragma unroll
    for (int off = 32; off > 0; off >>= 1) s += __shfl_down(s, off, 64);
    const float tot = __shfl(s, 0, 64);                       // broadcast

    const float inv = 1.0f / fmaxf(sqrtf(tot), 1e-12f);
    float4 vn;
    vn.x = v.x * inv; vn.y = v.y * inv; vn.z = v.z * inv; vn.w = v.w * inv;
    eTv[lane * N + row] = vn;          // transposed-float4 store (posted, async)

    if (lane == 0) sqn[row] = tot * inv * inv;   // matches ref's recompute on e_norm
}

__global__ __launch_bounds__(NTHR) void fused_kernel(
    const float4* __restrict__ eTv, const float* __restrict__ sqn,
    const int* __restrict__ labels,
    float* __restrict__ accum_sum, unsigned int* __restrict__ accum_cnt,
    unsigned int* __restrict__ done_cnt, float* __restrict__ out)
{
    const int i0   = blockIdx.x * NANCH;
    const int tid  = threadIdx.x;      // 0..N-1: one column each
    const int wave = tid >> 6, lane = tid & 63;

    __shared__ float4 ei4[NANCH][D4];  // normalized anchor rows
    __shared__ float  sqa[NANCH];
    __shared__ float  Drow[NANCH][N];  // distance rows (never touch global)
    __shared__ int    lab[N];
    __shared__ int    posList[NANCH][MAXPOS];
    __shared__ int    posCnt[NANCH];
    __shared__ float        sredS[NWAVE];
    __shared__ unsigned int sredC[NWAVE];

    // stage anchors (already normalized in eTv) + labels
    if (tid < NANCH * D4) {            // 128 threads: a = tid/64, k4 = tid%64
        const int a = tid >> 6, k4 = tid & (D4 - 1);
        ei4[a][k4] = eTv[k4 * N + (i0 + a)];
    }
    if (tid < NANCH) { sqa[tid] = sqn[i0 + tid]; posCnt[tid] = 0; }
    lab[tid] = labels[tid];
    __syncthreads();

    // ---- distance rows: thread tid owns column j = tid; 64 coalesced 16B loads
    float acc0 = 0.0f, acc1 = 0.0f;
    #pragma unroll 8
    for (int k4 = 0; k4 < D4; ++k4) {
        const float4 v  = eTv[k4 * N + tid];   // global_load_dwordx4, 8 in flight
        const float4 a0 = ei4[0][k4];          // ds_read_b128 broadcast (free)
        const float4 a1 = ei4[1][k4];
        acc0 += v.x*a0.x + v.y*a0.y + v.z*a0.z + v.w*a0.w;
        acc1 += v.x*a1.x + v.y*a1.y + v.z*a1.z + v.w*a1.w;
    }
    const float sqj = sqn[tid];
    {
        float d2 = fmaxf(sqa[0] + sqj - 2.0f * acc0, 0.0f);
        Drow[0][tid] = (d2 > 0.0f) ? sqrtf(d2) : 0.0f;   // ref: sqrt(where(pos,d2,1))*pos
        d2       = fmaxf(sqa[1] + sqj - 2.0f * acc1, 0.0f);
        Drow[1][tid] = (d2 > 0.0f) ? sqrtf(d2) : 0.0f;
    }
    __syncthreads();

    // ---- positive lists for both anchors
    const int lj = lab[tid];
    #pragma unroll
    for (int a = 0; a < NANCH; ++a) {
        const int ia = i0 + a;
        if (lj == lab[ia] && tid != ia)
            posList[a][atomicAdd(&posCnt[a], 1)] = tid;
    }
    __syncthreads();

    // ---- semihard accumulation; thread tid owns negative k = tid
    float        lsum = 0.0f;
    unsigned int lcnt = 0u;
    #pragma unroll
    for (int a = 0; a < NANCH; ++a) {
        const int   li = lab[i0 + a];
        const float dk = Drow[a][tid];         // an (if tid is a negative)
        if (lj != li) {
            const int np = posCnt[a];          // ~11 positives
            for (int p = 0; p < np; ++p) {
                const float tm = dk - Drow[a][posList[a][p]];   // an - ap
                if (tm > 0.0f && tm <= MARGIN_F) {
                    const float l = MARGIN_F - tm;              // max(MARGIN-tm,0)
                    lsum += l;
                    if (l > 0.0f) lcnt++;                       // strict losses>0 count
                }
            }
        }
    }

    // ---- block reduce, device accumulate, last-block finalize
    #pragma unroll
    for (int off = 32; off > 0; off >>= 1) {
        lsum += __shfl_down(lsum, off, 64);
        lcnt += __shfl_down(lcnt, off, 64);
    }
    if (lane == 0) { sredS[wave] = lsum; sredC[wave] = lcnt; }
    __syncthreads();

    if (tid == 0) {
        float        S = 0.0f;
        unsigned int C = 0u;
        #pragma unroll
        for (int w = 0; w < NWAVE; ++w) { S += sredS[w]; C += sredC[w]; }
        if (S != 0.0f || C != 0u) {
            atomicAdd(accum_sum, S);
            atomicAdd(accum_cnt, C);
        }
        __threadfence();                        // order adds before done++
        const unsigned int prev = atomicAdd(done_cnt, 1);
        if (prev == NBLK - 1) {                 // last block computes the mean
            const float        Sall = atomicAdd(accum_sum, 0.0f);
            const unsigned int Call = atomicAdd(accum_cnt, 0u);
            out[0] = (Call > 0u) ? (Sall / (float)Call) : 0.0f;
        }
    }
}

extern "C" void kernel_launch(void* const* d_in, const int* in_sizes, int n_in,
                              void* d_out, int out_size, void* d_ws, size_t ws_size,
                              hipStream_t stream) {
    const float* emb    = (const float*)d_in[0];   // (384, 256) fp32
    const int*   labels = (const int*)d_in[1];     // (384,) int32
    float*       out    = (float*)d_out;           // scalar fp32

    float*        accum_sum = (float*)d_ws;                    // [0]
    unsigned int* accum_cnt = (unsigned int*)accum_sum + 1;    // [1]
    unsigned int* done_cnt  = (unsigned int*)accum_sum + 2;    // [2]
    float4*       eTv = (float4*)((char*)d_ws + 16);           // N*DIM floats
    float*        sqn = (float*)((char*)d_ws + 16 + (size_t)N * DIM * 4);

    hipMemsetAsync(d_ws, 0, 16, stream);           // zero sum/cnt/done (graph-legal)
    norm_kernel<<<N, 64, 0, stream>>>(emb, eTv, sqn);
    fused_kernel<<<NBLK, NTHR, 0, stream>>>(eTv, sqn, labels,
                                            accum_sum, accum_cnt, done_cnt, out);
}